// Round 1
// 870.461 us; speedup vs baseline: 1.0469x; 1.0469x over previous
//
#include <hip/hip_runtime.h>

typedef unsigned short u16;
typedef unsigned int   u32;
typedef __bf16  bf16x8  __attribute__((ext_vector_type(8)));
typedef float   floatx4 __attribute__((ext_vector_type(4)));

#define BATCH 8
#define SEQ 4096
#define NTOK (BATCH*SEQ)          // 32768
#define BYTE_DIM 128
#define NUM_TABLES 32
#define BUCKETS 131072
#define EMBED 32
#define FEAT 1152                 // 128 + 32*32
#define HIDDEN 512
#define VOCAB 1024

__constant__ u32 PRIMES[48] = {
  2654435761u, 2246822519u, 3266489917u, 2028178513u, 1220703125u, 1610612741u,
  805306457u, 402653189u, 3674653429u, 2860486313u, 1073676287u, 2971215073u,
  1500450271u, 3267000013u, 2654435789u, 4049292737u, 2246822531u, 3266489927u,
  2028178519u, 1220703133u, 1610612743u, 805306459u, 402653191u, 3674653433u,
  2654435771u, 2246822527u, 3266489933u, 2028178529u, 1220703137u, 1610612747u,
  805306463u, 402653197u, 3674653441u, 2860486319u, 1073676293u, 2971215077u,
  1500450281u, 3267000017u, 2654435801u, 4049292743u, 2246822537u, 3266489939u,
  2028178531u, 1220703143u, 1610612753u, 805306467u, 402653201u, 3674653447u };

__constant__ int PAT_LEN[32] = {1,1,1,1,1,1,1,1,
                                2,2,2,2,2,2,2,2,2,2,2,2,
                                3,3,3,3,
                                2,2,2,2,2,2,2,2};
__constant__ int PAT_OFF[32][3] = {
  {1,0,0},{2,0,0},{3,0,0},{4,0,0},{5,0,0},{6,0,0},{7,0,0},{8,0,0},
  {1,2,0},{2,3,0},{3,4,0},{1,3,0},{2,4,0},{1,4,0},{1,5,0},{2,5,0},
  {3,5,0},{1,6,0},{2,6,0},{1,7,0},
  {1,2,3},{1,2,4},{1,3,5},{2,3,4},
  {1,8,0},{1,9,0},{1,10,0},{1,11,0},{1,12,0},{1,13,0},{1,14,0},{1,15,0}};

__device__ __forceinline__ u16 f2bf(float f) {
  u32 u = __builtin_bit_cast(u32, f);
  u = u + 0x7FFFu + ((u >> 16) & 1u);     // RNE (finite values only)
  return (u16)(u >> 16);
}
__device__ __forceinline__ float bf2f(u16 h) {
  return __builtin_bit_cast(float, (u32)h << 16);
}

__device__ __forceinline__ void gld16(const void* g, void* l) {
  __builtin_amdgcn_global_load_lds(
      (const __attribute__((address_space(1))) void*)g,
      (__attribute__((address_space(3))) void*)l, 16, 0, 0);
}

// ---------------- all 4 weight transposes in one launch
// tiles: in_w 16x36=576 | res_w0 16x16=256 | res_w1 256 | out_w 32x16=512 -> 1600
__global__ __launch_bounds__(256) void transpose_all(
    const float* __restrict__ in_w, const float* __restrict__ res_w,
    const float* __restrict__ out_w,
    u16* __restrict__ wT_in, u16* __restrict__ wT_r0,
    u16* __restrict__ wT_r1, u16* __restrict__ wT_out) {
  __shared__ float tile[32][33];
  int tid = blockIdx.x;
  const float* src; u16* dst; int K, N, bx, by;
  if (tid < 576) {
    src = in_w;  dst = wT_in;  K = FEAT;   N = HIDDEN;
    bx = tid & 15; by = tid >> 4;
  } else if (tid < 832) {
    int id = tid - 576;
    src = res_w; dst = wT_r0;  K = HIDDEN; N = HIDDEN;
    bx = id & 15; by = id >> 4;
  } else if (tid < 1088) {
    int id = tid - 832;
    src = res_w + (size_t)HIDDEN * HIDDEN; dst = wT_r1; K = HIDDEN; N = HIDDEN;
    bx = id & 15; by = id >> 4;
  } else {
    int id = tid - 1088;
    src = out_w; dst = wT_out; K = HIDDEN; N = VOCAB;
    bx = id & 31; by = id >> 5;
  }
  int tx = threadIdx.x & 31, ty = threadIdx.x >> 5;   // 32 x 8
  #pragma unroll
  for (int i = 0; i < 32; i += 8)
    tile[ty + i][tx] = src[(size_t)(by*32 + ty + i) * N + bx*32 + tx];
  __syncthreads();
  #pragma unroll
  for (int i = 0; i < 32; i += 8)
    dst[(size_t)(bx*32 + ty + i) * K + by*32 + tx] = f2bf(tile[tx][ty + i]);
}

// ---------------- feats: hash + gather -> bf16 [NTOK, 1152]
__global__ __launch_bounds__(256) void feats_kernel(
    const int* __restrict__ tokens, const float* __restrict__ byte_embed,
    const float* __restrict__ hash_tables, u16* __restrict__ feats) {
  int gid = blockIdx.x * 256 + threadIdx.x;    // NTOK*144 total
  int g = gid / 144;                           // token id
  int c = gid - g * 144;                       // 8-elem chunk within 1152
  int b = g >> 12, s = g & 4095;
  const float* src;
  int col;
  if (c < 16) {                                // byte-embed part
    int tok = tokens[g];
    col = c * 8;
    src = byte_embed + (size_t)tok * BYTE_DIM + col;
  } else {                                     // hash part
    int hc = c - 16;
    int tt = hc >> 2;                          // table
    int e0 = (hc & 3) * 8;                     // embed offset
    unsigned h = 0;
    int len = PAT_LEN[tt];
    #pragma unroll
    for (int k = 0; k < 3; ++k) {
      if (k < len) {
        int off = PAT_OFF[tt][k];
        int sp = s - off;
        unsigned tok = (sp >= 0) ? (unsigned)tokens[(b << 12) + sp] : 0u;
        unsigned prime = PRIMES[(tt * 3 + k) % 48] & 0x1FFFFu;
        h ^= (tok * prime) & 0x1FFFFu;
      }
    }
    src = hash_tables + ((size_t)tt * BUCKETS + (h & 0x1FFFFu)) * EMBED + e0;
    col = BYTE_DIM + tt * EMBED + e0;
  }
  float4 v0 = *(const float4*)src;
  float4 v1 = *(const float4*)(src + 4);
  union { u16 s[8]; uint4 v; } p;
  p.s[0]=f2bf(v0.x); p.s[1]=f2bf(v0.y); p.s[2]=f2bf(v0.z); p.s[3]=f2bf(v0.w);
  p.s[4]=f2bf(v1.x); p.s[5]=f2bf(v1.y); p.s[6]=f2bf(v1.z); p.s[7]=f2bf(v1.w);
  *(uint4*)&feats[(size_t)g * FEAT + col] = p.v;
}

// ---------------- bf16 MFMA GEMM, 128x128 tile, 2-phase double-buffered
// A: bf16 row-major [M,K]; BT: bf16 row-major [N,K]
// EPI 0: +bias, store bf16      EPI 2: +bias, store f32
template <int EPI>
__global__ __launch_bounds__(256) void gemm_bf16(
    const u16* __restrict__ A, const u16* __restrict__ BT,
    const float* __restrict__ bias,
    void* __restrict__ Cout, int M, int N, int K) {
  __shared__ __align__(16) u16 As[2][128 * 32];
  __shared__ __align__(16) u16 Bs[2][128 * 32];
  const int t = threadIdx.x;
  const int w = t >> 6, l = t & 63;
  const int m0 = blockIdx.y * 128;
  const int n0 = blockIdx.x * 128;
  const int wm = (w >> 1) * 64, wn = (w & 1) * 64;
  const int r16 = l & 15, hk = (l >> 4) * 8;

  floatx4 acc[4][4];
  #pragma unroll
  for (int mi = 0; mi < 4; ++mi)
    #pragma unroll
    for (int ni = 0; ni < 4; ++ni)
      acc[mi][ni] = (floatx4){0.f, 0.f, 0.f, 0.f};

  auto stage = [&](int b, int k0) {
    #pragma unroll
    for (int j = 0; j < 2; ++j) {
      int c = j * 256 + t;          // 16B chunk id (wave-uniform base + lane*16)
      int row = c >> 2, q = c & 3;
      gld16(A  + (size_t)(m0 + row) * K + k0 + q * 8, &As[b][c * 8]);
      gld16(BT + (size_t)(n0 + row) * K + k0 + q * 8, &Bs[b][c * 8]);
    }
  };

  stage(0, 0);
  __syncthreads();                  // vmcnt(0) drain + barrier
  int cur = 0;
  const int nk = K >> 5;
  for (int kt = 0; kt < nk; ++kt) {
    if (kt + 1 < nk) stage(cur ^ 1, (kt + 1) * 32);   // prefetch next tile
    bf16x8 af[4], bfr[4];
    #pragma unroll
    for (int mi = 0; mi < 4; ++mi)
      af[mi] = *(const bf16x8*)&As[cur][(wm + mi * 16 + r16) * 32 + hk];
    #pragma unroll
    for (int ni = 0; ni < 4; ++ni)
      bfr[ni] = *(const bf16x8*)&Bs[cur][(wn + ni * 16 + r16) * 32 + hk];
    #pragma unroll
    for (int mi = 0; mi < 4; ++mi)
      #pragma unroll
      for (int ni = 0; ni < 4; ++ni)
        acc[mi][ni] = __builtin_amdgcn_mfma_f32_16x16x32_bf16(
            af[mi], bfr[ni], acc[mi][ni], 0, 0, 0);
    __syncthreads();                // prefetch done + all reads of cur done
    cur ^= 1;
  }

  // epilogue: D mapping col = lane&15, row = (lane>>4)*4 + r
  const int q4 = (l >> 4) * 4;
  #pragma unroll
  for (int mi = 0; mi < 4; ++mi) {
    #pragma unroll
    for (int ni = 0; ni < 4; ++ni) {
      int col = n0 + wn + ni * 16 + r16;
      float bn = bias[col];
      int rowb = m0 + wm + mi * 16 + q4;
      #pragma unroll
      for (int r = 0; r < 4; ++r) {
        float v = acc[mi][ni][r] + bn;
        size_t off = (size_t)(rowb + r) * N + col;
        if (EPI == 0) {
          ((u16*)Cout)[off] = f2bf(v);
        } else {
          ((float*)Cout)[off] = v;
        }
      }
    }
  }
}

// ---------------- fused residual layer: Y = LN(relu(A@W + b) + A)
// 128x512 full-N tile, 512 threads (8 waves: 2M x 4N), dbuf LDS, 1 barrier/K-step.
// A,Y: [NTOK, 512] bf16.  WT: [512,512] bf16 (row n holds W[:,n]).
__global__ __launch_bounds__(512) void fused_layer(
    const u16* __restrict__ A, const u16* __restrict__ WT,
    const float* __restrict__ bias,
    const float* __restrict__ lw, const float* __restrict__ lb,
    u16* __restrict__ Y) {
  __shared__ __align__(16) u16 As[2][128 * 32];   // 16 KB
  __shared__ __align__(16) u16 Bs[2][512 * 32];   // 64 KB
  __shared__ float red1[128][4];
  __shared__ float red2[128][4];
  __shared__ float2 muinv[128];

  const int t = threadIdx.x;
  const int w = t >> 6, l = t & 63;
  const int m0 = blockIdx.x * 128;
  const int wm = (w >> 2) * 64;            // 0 or 64
  const int wn = (w & 3) * 128;            // 0,128,256,384
  const int r16 = l & 15, hk = (l >> 4) * 8, q4 = (l >> 4) * 4;

  floatx4 acc[4][8];                       // 128 VGPR accumulator
  #pragma unroll
  for (int mi = 0; mi < 4; ++mi)
    #pragma unroll
    for (int ni = 0; ni < 8; ++ni)
      acc[mi][ni] = (floatx4){0.f, 0.f, 0.f, 0.f};

  auto stage = [&](int b, int k0) {
    {                                       // A tile: 512 chunks, 1 per thread
      int row = t >> 2, q = t & 3;
      gld16(A + (size_t)(m0 + row) * HIDDEN + k0 + q * 8, &As[b][t * 8]);
    }
    #pragma unroll
    for (int j = 0; j < 4; ++j) {           // B tile: 2048 chunks, 4 per thread
      int c = j * 512 + t;
      int row = c >> 2, q = c & 3;
      gld16(WT + (size_t)row * HIDDEN + k0 + q * 8, &Bs[b][c * 8]);
    }
  };

  stage(0, 0);
  __syncthreads();
  int cur = 0;
  #pragma unroll 1
  for (int kt = 0; kt < 16; ++kt) {
    if (kt < 15) stage(cur ^ 1, (kt + 1) * 32);
    bf16x8 af[4], bfr[8];
    #pragma unroll
    for (int mi = 0; mi < 4; ++mi)
      af[mi] = *(const bf16x8*)&As[cur][(wm + mi * 16 + r16) * 32 + hk];
    #pragma unroll
    for (int ni = 0; ni < 8; ++ni)
      bfr[ni] = *(const bf16x8*)&Bs[cur][(wn + ni * 16 + r16) * 32 + hk];
    #pragma unroll
    for (int mi = 0; mi < 4; ++mi)
      #pragma unroll
      for (int ni = 0; ni < 8; ++ni)
        acc[mi][ni] = __builtin_amdgcn_mfma_f32_16x16x32_bf16(
            af[mi], bfr[ni], acc[mi][ni], 0, 0, 0);
    __syncthreads();
    cur ^= 1;
  }

  // ---- epilogue: relu(+bias) + residual, row sums for LN
  float bn[8], lwv[8], lbv[8];
  #pragma unroll
  for (int ni = 0; ni < 8; ++ni) {
    int col = wn + ni * 16 + r16;
    bn[ni] = bias[col]; lwv[ni] = lw[col]; lbv[ni] = lb[col];
  }
  #pragma unroll
  for (int mi = 0; mi < 4; ++mi) {
    #pragma unroll
    for (int r = 0; r < 4; ++r) {
      int rl = wm + mi * 16 + q4 + r;             // local row 0..127
      size_t gbase = (size_t)(m0 + rl) * HIDDEN;
      float s1 = 0.f, s2 = 0.f;
      #pragma unroll
      for (int ni = 0; ni < 8; ++ni) {
        float rv = bf2f(A[gbase + wn + ni * 16 + r16]);     // residual (L2-hot)
        float x = fmaxf(acc[mi][ni][r] + bn[ni], 0.f) + rv;
        acc[mi][ni][r] = x;
        s1 += x; s2 += x * x;
      }
      #pragma unroll
      for (int d = 1; d < 16; d <<= 1) {          // reduce across 16-lane group
        s1 += __shfl_xor(s1, d);
        s2 += __shfl_xor(s2, d);
      }
      if (r16 == 0) { red1[rl][w & 3] = s1; red2[rl][w & 3] = s2; }
    }
  }
  __syncthreads();
  if (t < 128) {
    float s1 = red1[t][0] + red1[t][1] + red1[t][2] + red1[t][3];
    float s2 = red2[t][0] + red2[t][1] + red2[t][2] + red2[t][3];
    float mu = s1 * (1.f / HIDDEN);
    float var = s2 * (1.f / HIDDEN) - mu * mu;
    muinv[t] = make_float2(mu, rsqrtf(fmaxf(var, 0.f) + 1e-5f));
  }
  __syncthreads();
  #pragma unroll
  for (int mi = 0; mi < 4; ++mi) {
    #pragma unroll
    for (int r = 0; r < 4; ++r) {
      int rl = wm + mi * 16 + q4 + r;
      float2 mv = muinv[rl];
      size_t gbase = (size_t)(m0 + rl) * HIDDEN;
      #pragma unroll
      for (int ni = 0; ni < 8; ++ni) {
        float y = (acc[mi][ni][r] - mv.x) * mv.y * lwv[ni] + lbv[ni];
        Y[gbase + wn + ni * 16 + r16] = f2bf(y);
      }
    }
  }
}

extern "C" void kernel_launch(void* const* d_in, const int* in_sizes, int n_in,
                              void* d_out, int out_size, void* d_ws, size_t ws_size,
                              hipStream_t stream) {
  const int*   tokens      = (const int*)  d_in[0];
  const float* byte_embed  = (const float*)d_in[1];
  const float* hash_tables = (const float*)d_in[2];
  const float* in_w        = (const float*)d_in[3];
  const float* in_b        = (const float*)d_in[4];
  const float* res_w       = (const float*)d_in[5];
  const float* res_b       = (const float*)d_in[6];
  const float* ln_w        = (const float*)d_in[7];
  const float* ln_b        = (const float*)d_in[8];
  const float* out_w       = (const float*)d_in[9];
  const float* out_b       = (const float*)d_in[10];
  float* out = (float*)d_out;

  char* ws = (char*)d_ws;
  u16* wT_in  = (u16*)ws; ws += (size_t)HIDDEN * FEAT * 2;       // [512,1152]
  u16* wT_r0  = (u16*)ws; ws += (size_t)HIDDEN * HIDDEN * 2;     // [512,512]
  u16* wT_r1  = (u16*)ws; ws += (size_t)HIDDEN * HIDDEN * 2;
  u16* wT_out = (u16*)ws; ws += (size_t)VOCAB * HIDDEN * 2;      // [1024,512]
  u16* feats  = (u16*)ws; ws += (size_t)NTOK * FEAT * 2;         // 75.5 MB
  u16* hA     = (u16*)ws; ws += (size_t)NTOK * HIDDEN * 2;       // 33.5 MB
  u16* hB     = (u16*)ws;                                        // 33.5 MB

  // weight prep (bf16 + transpose), single launch
  transpose_all<<<1600, 256, 0, stream>>>(in_w, res_w, out_w,
                                          wT_in, wT_r0, wT_r1, wT_out);

  // feats gather
  feats_kernel<<<(NTOK * 144) / 256, 256, 0, stream>>>(tokens, byte_embed, hash_tables, feats);

  // h = feats @ in_w + in_b  -> bf16
  gemm_bf16<0><<<dim3(HIDDEN/128, NTOK/128), 256, 0, stream>>>(
      feats, wT_in, in_b, hA, NTOK, HIDDEN, FEAT);

  // layer 0 fused: hB = LN(relu(hA @ W0 + b0) + hA)
  fused_layer<<<NTOK/128, 512, 0, stream>>>(hA, wT_r0, res_b, ln_w, ln_b, hB);

  // layer 1 fused: hA = LN(relu(hB @ W1 + b1) + hB)
  fused_layer<<<NTOK/128, 512, 0, stream>>>(hB, wT_r1, res_b + HIDDEN,
                                            ln_w + HIDDEN, ln_b + HIDDEN, hA);

  // out = hA @ out_w + out_b -> f32
  gemm_bf16<2><<<dim3(VOCAB/128, NTOK/128), 256, 0, stream>>>(
      hA, wT_out, out_b, out, NTOK, VOCAB, HIDDEN);
}